// Round 5
// baseline (779.442 us; speedup 1.0000x reference)
//
#include <hip/hip_runtime.h>
#include <hip/hip_bf16.h>
#include <math.h>

// Problem constants (fixed by reference)
#define NT  8192
#define EMB 512
#define DFF 2048
#define EPS 1e-5f
#define SCALE 0.04419417382415922f  // 1/sqrt(512)

typedef __hip_bfloat16 bf16;
typedef __attribute__((ext_vector_type(8))) short short8;
typedef __attribute__((ext_vector_type(4))) float floatx4;

#define MFMA_BF16(a, b, c) __builtin_amdgcn_mfma_f32_16x16x32_bf16((a), (b), (c), 0, 0, 0)
#define MFMA_FP8(a, b, c)  __builtin_amdgcn_mfma_f32_16x16x32_fp8_fp8((a), (b), (c), 0, 0, 0)

// B1: LDS-visibility barrier only; global/staging loads stay in flight
#define BARRIER_LGKM() asm volatile("s_waitcnt lgkmcnt(0)\ns_barrier" ::: "memory")
// B2: drain everything
#define BARRIER_ALL()  asm volatile("s_waitcnt vmcnt(0) lgkmcnt(0)\ns_barrier" ::: "memory")

__device__ __forceinline__ void async16(const void* g, void* l) {
  __builtin_amdgcn_global_load_lds(
      (const __attribute__((address_space(1))) void*)g,
      (__attribute__((address_space(3))) void*)l, 16, 0, 0);
}

// ---------------- LayerNorm1: fp32 in -> bf16 + fp8(e4m3) out ----------------
__global__ __launch_bounds__(512) void ln_kernel(const float* __restrict__ in,
                                                 const float* __restrict__ g,
                                                 const float* __restrict__ b,
                                                 bf16* __restrict__ out,
                                                 unsigned char* __restrict__ out8) {
  const int row = blockIdx.x;
  const int tid = threadIdx.x;
  float v = in[(size_t)row * EMB + tid];
  float s = v, ss = v * v;
#pragma unroll
  for (int m = 1; m < 64; m <<= 1) {
    s += __shfl_xor(s, m, 64);
    ss += __shfl_xor(ss, m, 64);
  }
  __shared__ float ps[8], pss[8], mu_s, ri_s;
  const int wave = tid >> 6;
  if ((tid & 63) == 0) { ps[wave] = s; pss[wave] = ss; }
  __syncthreads();
  if (tid == 0) {
    float S = 0.f, SS = 0.f;
#pragma unroll
    for (int w = 0; w < 8; ++w) { S += ps[w]; SS += pss[w]; }
    float mu = S * (1.0f / EMB);
    float var = SS * (1.0f / EMB) - mu * mu;
    mu_s = mu;
    ri_s = rsqrtf(var + EPS);
  }
  __syncthreads();
  float y = (v - mu_s) * ri_s * g[tid] + b[tid];
  out[(size_t)row * EMB + tid] = __float2bfloat16(y);
  int p8 = __builtin_amdgcn_cvt_pk_fp8_f32(y, y, 0, false);
  out8[(size_t)row * EMB + tid] = (unsigned char)(p8 & 0xff);
}

// ---------------- transpose + cast to bf16: out[c][r] = in[r][c] ----------------
template <typename Tin>
__global__ void transpose_cast(const Tin* __restrict__ in, bf16* __restrict__ out,
                               int R, int C) {
  __shared__ float tile[32][33];
  const int r0 = blockIdx.x * 32, c0 = blockIdx.y * 32;
  const int x = threadIdx.x, y = threadIdx.y;  // block (32, 8)
#pragma unroll
  for (int i = 0; i < 4; ++i)
    tile[y + 8 * i][x] = (float)in[(size_t)(r0 + y + 8 * i) * C + c0 + x];
  __syncthreads();
#pragma unroll
  for (int i = 0; i < 4; ++i)
    out[(size_t)(c0 + y + 8 * i) * R + r0 + x] = __float2bfloat16(tile[x][y + 8 * i]);
}

// ---------------- Flash attention v5 ----------------
// 1024 threads = 16 waves; BM=64, BN=64; split-n 2-way interleaved (grid (128,2)).
// Wave w: qt=w&3 (16-q slice), nh=w>>2 (16-n slice) for S^T; PV d-slice [32w,+32).
// fp8 QK (S^T = K8 . Q8^T), bf16 PV. Double-buffered K tile (2x32KB): stage next at
// iter top, drained at B2 with a full iteration of cover. spi bias one iter ahead.
__global__ __launch_bounds__(1024, 4) void flash_attn(const unsigned char* __restrict__ nx8,
                                                      const bf16* __restrict__ nxT,
                                                      const float* __restrict__ spi,
                                                      bf16* __restrict__ Opart,
                                                      float* __restrict__ mpart,
                                                      float* __restrict__ lpart) {
  // LDS: kbuf 2x32768 | p_s 64x72x2=9216 | wmax 4x64x4 | wsum 4x64x4 | alpha 64x4
  __shared__ __align__(16) char smem[65536 + 9216 + 1024 + 1024 + 256];
  char* kbuf = smem;
  short* p_s = (short*)(smem + 65536);
  float* wmax = (float*)(smem + 74752);
  float* wsum = (float*)(smem + 75776);
  float* alpha_s = (float*)(smem + 76800);

  const int tid = threadIdx.x;
  const int wave = tid >> 6;
  const int lane = tid & 63;
  const int quad = lane >> 4;
  const int l16 = lane & 15;
  const int qh = quad >> 1;
  const int qt = wave & 3;   // q-slice
  const int nh = wave >> 2;  // n-slice (0..3)
  const int q0 = blockIdx.x * 64;
  const int s = blockIdx.y;

  floatx4 O[4][2];  // [qt2][dt]: q = qt2*16+quad*4+r, d = wave*32+dt*16+l16
#pragma unroll
  for (int i = 0; i < 4; ++i) {
    O[i][0] = (floatx4){0.f, 0.f, 0.f, 0.f};
    O[i][1] = (floatx4){0.f, 0.f, 0.f, 0.f};
  }
  float m_reg = -INFINITY;  // per-lane q = qt*16+l16 (quad-replicated)
  float l_reg = 0.f;

  // Q fp8 B-frags in regs: row q0+qt*16+l16, k = ks*32 + quad*8
  long qf8[16];
  {
    const char* qsrc = (const char*)nx8 + (size_t)(q0 + qt * 16 + l16) * EMB + quad * 8;
#pragma unroll
    for (int ks = 0; ks < 16; ++ks) qf8[ks] = *(const long*)(qsrc + ks * 32);
  }
  // stage K tile 0 into buf0 (XOR 16B-chunk swizzle; dest = wave-uniform + lane*16)
#pragma unroll
  for (int t = 0; t < 2; ++t) {
    int c = t * 1024 + tid;  // 0..2047
    int row = c >> 5, ch = c & 31;
    async16(nx8 + (size_t)(s * 64 + row) * EMB + ((ch ^ (row & 7)) << 4), kbuf + c * 16);
  }
  // spi bias prefetch for iter 0
  const float* spib = spi + (size_t)(q0 + qt * 16 + l16) * NT + nh * 16 + quad * 4;
  floatx4 biasC = *(const floatx4*)(spib + s * 64);
  BARRIER_ALL();

  const int krow = nh * 16 + l16;
  const int rx = krow & 7;
  const short* vb = (const short*)nxT + (size_t)(wave * 32 + l16) * NT + quad * 8;

  for (int i = 0; i < 64; ++i) {
    const int n0 = s * 64 + i * 128;
    const char* kb = kbuf + (i & 1) * 32768 + krow * 512 + (quad & 1) * 8;

    // ---- stage NEXT K tile into other buffer + prefetch NEXT spi bias
    const int nn = s * 64 + (i < 63 ? (i + 1) : 63) * 128;
    {
      char* kn = kbuf + ((i + 1) & 1) * 32768;
#pragma unroll
      for (int t = 0; t < 2; ++t) {
        int c = t * 1024 + tid;
        int row = c >> 5, ch = c & 31;
        async16(nx8 + (size_t)(nn + row) * EMB + ((ch ^ (row & 7)) << 4), kn + c * 16);
      }
    }
    floatx4 biasN = *(const floatx4*)(spib + nn);

    // ---- QK: one S^T tile per wave (16n x 16q), 2 interleaved chains
    floatx4 acc0 = (floatx4){0.f, 0.f, 0.f, 0.f}, acc1 = (floatx4){0.f, 0.f, 0.f, 0.f};
#pragma unroll
    for (int ks = 0; ks < 16; ks += 2) {
      long a0 = *(const long*)(kb + (((ks * 2 + qh) ^ rx) << 4));
      acc0 = MFMA_FP8(a0, qf8[ks], acc0);
      long a1 = *(const long*)(kb + ((((ks + 1) * 2 + qh) ^ rx) << 4));
      acc1 = MFMA_FP8(a1, qf8[ks + 1], acc1);
    }
    float sv[4];
#pragma unroll
    for (int r = 0; r < 4; ++r) sv[r] = (acc0[r] + acc1[r]) * SCALE + biasC[r];
    biasC = biasN;
    float pm = fmaxf(fmaxf(sv[0], sv[1]), fmaxf(sv[2], sv[3]));
    pm = fmaxf(pm, __shfl_xor(pm, 16, 64));
    pm = fmaxf(pm, __shfl_xor(pm, 32, 64));
    if (quad == 0) wmax[nh * 64 + qt * 16 + l16] = pm;
    BARRIER_LGKM();  // B1: k_s reads done; wmax visible (staging stays in flight)

    // ---- online softmax (per-lane q state, quad-replicated)
    const int q = qt * 16 + l16;
    float tm = fmaxf(fmaxf(wmax[q], wmax[64 + q]), fmaxf(wmax[128 + q], wmax[192 + q]));
    float mn = fmaxf(m_reg, tm);
    float al = __expf(m_reg - mn);
    m_reg = mn;
    float pv[4], psum = 0.f;
#pragma unroll
    for (int r = 0; r < 4; ++r) {
      pv[r] = __expf(sv[r] - mn);
      psum += pv[r];
    }
    psum += __shfl_xor(psum, 16, 64);
    psum += __shfl_xor(psum, 32, 64);
    if (quad == 0) {
      wsum[nh * 64 + q] = psum;
      if (nh == 0) alpha_s[q] = al;
    }
    {
      union { short s4[4]; long l; } pk;
#pragma unroll
      for (int r = 0; r < 4; ++r)
        pk.s4[r] = __bfloat16_as_short(__float2bfloat16(pv[r]));
      *(long*)(p_s + q * 72 + nh * 16 + quad * 4) = pk.l;
    }
    BARRIER_ALL();  // B2: p_s/wsum/alpha visible; next-K staging drained (full-iter cover)

    l_reg = al * l_reg + wsum[q] + wsum[64 + q] + wsum[128 + q] + wsum[192 + q];

    // ---- O rescale (skip when all alphas == 1)
    floatx4 a4[4];
#pragma unroll
    for (int qt2 = 0; qt2 < 4; ++qt2)
      a4[qt2] = *(const floatx4*)(alpha_s + qt2 * 16 + quad * 4);
    int allone = 1;
#pragma unroll
    for (int qt2 = 0; qt2 < 4; ++qt2)
#pragma unroll
      for (int r = 0; r < 4; ++r) allone &= (a4[qt2][r] == 1.0f);
    if (!__all(allone)) {
#pragma unroll
      for (int qt2 = 0; qt2 < 4; ++qt2)
#pragma unroll
        for (int dt = 0; dt < 2; ++dt)
#pragma unroll
          for (int r = 0; r < 4; ++r) O[qt2][dt][r] *= a4[qt2][r];
    }
    // ---- PV: V-frags inline (L2-hot), P from p_s
    short8 v00 = *(const short8*)(vb + n0);
    short8 v01 = *(const short8*)(vb + n0 + 32);
    short8 v10 = *(const short8*)(vb + (size_t)16 * NT + n0);
    short8 v11 = *(const short8*)(vb + (size_t)16 * NT + n0 + 32);
#pragma unroll
    for (int qt2 = 0; qt2 < 4; ++qt2) {
      short8 pa0 = *(const short8*)(p_s + (qt2 * 16 + l16) * 72 + quad * 8);
      short8 pa1 = *(const short8*)(p_s + (qt2 * 16 + l16) * 72 + 32 + quad * 8);
      O[qt2][0] = MFMA_BF16(pa0, v00, O[qt2][0]);
      O[qt2][0] = MFMA_BF16(pa1, v01, O[qt2][0]);
      O[qt2][1] = MFMA_BF16(pa0, v10, O[qt2][1]);
      O[qt2][1] = MFMA_BF16(pa1, v11, O[qt2][1]);
    }
  }
  __syncthreads();

  // ---- epilogue: coalesced store via LDS bounce (2 passes of 32 q-rows)
  short* ebuf = (short*)smem;  // [32][520], aliases kbuf (dead)
#pragma unroll
  for (int p = 0; p < 2; ++p) {
    __syncthreads();
#pragma unroll
    for (int hh = 0; hh < 2; ++hh) {
      const int qt2 = 2 * p + hh;
      const int lrow = hh * 16 + quad * 4;
#pragma unroll
      for (int dt = 0; dt < 2; ++dt)
#pragma unroll
        for (int r = 0; r < 4; ++r)
          ebuf[(lrow + r) * 520 + wave * 32 + dt * 16 + l16] =
              __bfloat16_as_short(__float2bfloat16(O[qt2][dt][r]));
    }
    __syncthreads();
#pragma unroll
    for (int t = 0; t < 2; ++t) {
      int c = t * 1024 + tid;  // 0..2047 chunks of 8 shorts
      int row = c >> 6, ch = c & 63;
      short8 v = *(const short8*)(ebuf + row * 520 + ch * 8);
      *(short8*)((short*)Opart + ((size_t)s * NT + q0 + p * 32 + row) * EMB + ch * 8) = v;
    }
  }
  if (nh == 0 && quad == 0) {
    mpart[s * NT + q0 + qt * 16 + l16] = m_reg;
    lpart[s * NT + q0 + qt * 16 + l16] = l_reg;
  }
}

// ---------------- merge split-n partials + residual + LayerNorm2 fused ----------
__global__ __launch_bounds__(512) void merge_ln(const bf16* __restrict__ Opart,
                                                const float* __restrict__ mpart,
                                                const float* __restrict__ lpart,
                                                const float* __restrict__ x,
                                                const float* __restrict__ g,
                                                const float* __restrict__ b,
                                                float* __restrict__ out,
                                                bf16* __restrict__ h) {
  const int row = blockIdx.x;
  const int tid = threadIdx.x;
  float m1 = mpart[row], m2 = mpart[NT + row];
  float l1 = lpart[row], l2 = lpart[NT + row];
  float mm = fmaxf(m1, m2);
  float a1 = __expf(m1 - mm), a2 = __expf(m2 - mm);
  float linv = 1.0f / (a1 * l1 + a2 * l2);
  float o1 = __bfloat162float(Opart[(size_t)row * EMB + tid]);
  float o2 = __bfloat162float(Opart[((size_t)NT + row) * EMB + tid]);
  float v = x[(size_t)row * EMB + tid] + (a1 * o1 + a2 * o2) * linv;
  out[(size_t)row * EMB + tid] = v;
  float sum = v, ssum = v * v;
#pragma unroll
  for (int m = 1; m < 64; m <<= 1) {
    sum += __shfl_xor(sum, m, 64);
    ssum += __shfl_xor(ssum, m, 64);
  }
  __shared__ float ps[8], pss[8], mu_s, ri_s;
  const int wave = tid >> 6;
  if ((tid & 63) == 0) { ps[wave] = sum; pss[wave] = ssum; }
  __syncthreads();
  if (tid == 0) {
    float S = 0.f, SS = 0.f;
#pragma unroll
    for (int w = 0; w < 8; ++w) { S += ps[w]; SS += pss[w]; }
    float mu = S * (1.0f / EMB);
    float var = SS * (1.0f / EMB) - mu * mu;
    mu_s = mu;
    ri_s = rsqrtf(var + EPS);
  }
  __syncthreads();
  h[(size_t)row * EMB + tid] = __float2bfloat16((v - mu_s) * ri_s * g[tid] + b[tid]);
}

// ---------------- BT-GEMM (dbuf): C[i][j] = sum_k A[i][k]*BT[j][k], 128x128 ----------
// MODE 0: C = relu(acc + bias[j]) -> bf16    MODE 1: C = acc + bias[j] + resid -> fp32
template <int MODE>
__global__ __launch_bounds__(256) void gemm_bt(const bf16* __restrict__ A,
                                               const bf16* __restrict__ BT,
                                               const float* __restrict__ bias,
                                               const float* __restrict__ resid,
                                               void* __restrict__ Cout, int M, int Nn,
                                               int K) {
  __shared__ __align__(16) short a_s[2][128 * 32];
  __shared__ __align__(16) short b_s[2][128 * 32];
  const int tid = threadIdx.x;
  const int wave = tid >> 6, lane = tid & 63, quad = lane >> 4, l16 = lane & 15;
  const int m0 = blockIdx.x * 128, n0 = blockIdx.y * 128;
  const int mh = (wave & 1) * 64, nhh = (wave >> 1) * 64;

  floatx4 acc[4][4];
#pragma unroll
  for (int i = 0; i < 4; ++i)
#pragma unroll
    for (int j = 0; j < 4; ++j) acc[i][j] = (floatx4){0.f, 0.f, 0.f, 0.f};

  // stage k0=0 into buf0
#pragma unroll
  for (int t = 0; t < 2; ++t) {
    int c = (wave * 2 + t) * 64 + lane;
    int row = c >> 2, pc = c & 3;
    int sc = (pc ^ ((row >> 1) & 3)) << 3;
    async16(A + (size_t)(m0 + row) * K + sc, a_s[0] + (wave * 2 + t) * 512);
    async16(BT + (size_t)(n0 + row) * K + sc, b_s[0] + (wave * 2 + t) * 512);
  }
  BARRIER_ALL();

  const int nk = K >> 5;
  for (int ki = 0; ki < nk; ++ki) {
    // stage next k-tile into the other buffer (in flight through this iter)
    if (ki + 1 < nk) {
      const int k0 = (ki + 1) << 5;
#pragma unroll
      for (int t = 0; t < 2; ++t) {
        int c = (wave * 2 + t) * 64 + lane;
        int row = c >> 2, pc = c & 3;
        int sc = (pc ^ ((row >> 1) & 3)) << 3;
        async16(A + (size_t)(m0 + row) * K + k0 + sc, a_s[(ki + 1) & 1] + (wave * 2 + t) * 512);
        async16(BT + (size_t)(n0 + row) * K + k0 + sc, b_s[(ki + 1) & 1] + (wave * 2 + t) * 512);
      }
    }
    const short* ab = a_s[ki & 1];
    const short* bb = b_s[ki & 1];
    short8 af[4], bfr[4];
#pragma unroll
    for (int i = 0; i < 4; ++i) {
      int ar = mh + i * 16 + l16;
      af[i] = *(const short8*)(ab + ar * 32 + ((quad ^ ((ar >> 1) & 3)) << 3));
      int br = nhh + i * 16 + l16;
      bfr[i] = *(const short8*)(bb + br * 32 + ((quad ^ ((br >> 1) & 3)) << 3));
    }
#pragma unroll
    for (int i = 0; i < 4; ++i)
#pragma unroll
      for (int j = 0; j < 4; ++j) acc[i][j] = MFMA_BF16(af[i], bfr[j], acc[i][j]);
    BARRIER_ALL();  // staging drained (had the whole MFMA phase); LDS reads done
  }
#pragma unroll
  for (int i = 0; i < 4; ++i)
#pragma unroll
    for (int j = 0; j < 4; ++j)
#pragma unroll
      for (int r = 0; r < 4; ++r) {
        int row = m0 + mh + i * 16 + quad * 4 + r;
        int col = n0 + nhh + j * 16 + l16;
        float v = acc[i][j][r] + bias[col];
        if (MODE == 0) {
          ((bf16*)Cout)[(size_t)row * Nn + col] = __float2bfloat16(fmaxf(v, 0.f));
        } else {
          size_t idx = (size_t)row * Nn + col;
          ((float*)Cout)[idx] = v + resid[idx];
        }
      }
}

// ---------------- launch ----------------
extern "C" void kernel_launch(void* const* d_in, const int* in_sizes, int n_in,
                              void* d_out, int out_size, void* d_ws, size_t ws_size,
                              hipStream_t stream) {
  const float* x = (const float*)d_in[0];
  const float* spi = (const float*)d_in[2];
  const float* g1 = (const float*)d_in[3];
  const float* b1 = (const float*)d_in[4];
  const float* g2 = (const float*)d_in[5];
  const float* b2 = (const float*)d_in[6];
  const float* W1 = (const float*)d_in[7];
  const float* bb1 = (const float*)d_in[8];
  const float* W2 = (const float*)d_in[9];
  const float* bb2 = (const float*)d_in[10];
  float* out = (float*)d_out;

  // ws (60 MB): nx[0,8) nxT[8,16) h/nx8[16,24) t/Opart[24,56) w1t[56,58) w2t[58,60)
  char* ws = (char*)d_ws;
  bf16* nx = (bf16*)(ws);
  bf16* nxT = (bf16*)(ws + (8ull << 20));
  unsigned char* nx8 = (unsigned char*)(ws + (16ull << 20));
  bf16* h = (bf16*)(ws + (16ull << 20));
  bf16* t = (bf16*)(ws + (24ull << 20));
  bf16* Opart = (bf16*)(ws + (24ull << 20));
  float* mpart = (float*)(ws + (42ull << 20));
  float* lpart = (float*)(ws + (42ull << 20) + (1ull << 18));
  bf16* w1t = (bf16*)(ws + (56ull << 20));
  bf16* w2t = (bf16*)(ws + (58ull << 20));

  ln_kernel<<<NT, 512, 0, stream>>>(x, g1, b1, nx, nx8);
  transpose_cast<bf16><<<dim3(NT / 32, EMB / 32), dim3(32, 8), 0, stream>>>(nx, nxT, NT, EMB);
  transpose_cast<float><<<dim3(EMB / 32, DFF / 32), dim3(32, 8), 0, stream>>>(W1, w1t, EMB, DFF);
  transpose_cast<float><<<dim3(DFF / 32, EMB / 32), dim3(32, 8), 0, stream>>>(W2, w2t, DFF, EMB);
  flash_attn<<<dim3(NT / 64, 2), 1024, 0, stream>>>(nx8, nxT, spi, Opart, mpart, lpart);
  merge_ln<<<NT, 512, 0, stream>>>(Opart, mpart, lpart, x, g2, b2, out, h);
  gemm_bt<0><<<dim3(NT / 128, DFF / 128), 256, 0, stream>>>(h, w1t, bb1, nullptr, (void*)t, NT, DFF, EMB);
  gemm_bt<1><<<dim3(NT / 128, EMB / 128), 256, 0, stream>>>(t, w2t, bb2, out, (void*)out, NT, EMB, DFF);
}